// Round 2
// baseline (72817.218 us; speedup 1.0000x reference)
//
#include <hip/hip_runtime.h>
#include <math.h>

#define NBLK 256
#define NTHR 256
#define NK 8
#define KC 96           // 768 / NK

__device__ __forceinline__ float fsigmoid(float x){ return 1.0f/(1.0f + __expf(-x)); }
__device__ __forceinline__ float ftanh(float x){
    float ax = fabsf(x);
    if (ax > 15.0f) return copysignf(1.0f, x);
    float e = __expf(2.0f*x);
    return (e - 1.0f) / (e + 1.0f);
}

struct Params {
    const float* input_p; const float* mask_p; const float* input_q; const float* mask_q;
    const float* W_ih; const float* W_hh; const float* bias;
    const float* ln_i_g; const float* ln_i_b; const float* ln_h_g; const float* ln_h_b;
    const float* ln_c_g; const float* ln_c_b;
    const float* Wq; const float* Wp; const float* Wr; const float* w_att; const float* b_att;
    float* out;
    float* qWq;     // [2][16][128][768]
    float* hbuf;    // [2][16][768]   (cbuf directly after -> contiguous zero)
    float* cbuf;    // [2][16][768]
    float* sP;      // [2][NK][16][768]
    float* whP;     // [NK][16][3072]
    float* cwP;     // [NK][16][3072]
    float* wiP;     // [NK][16][3072]
    float* escore;  // [16][128]
    float* wghtd;   // [16][768]
    unsigned* bar;  // [2]: count, gen
};

// ---------------- grid barrier (sense-reversing, agent scope) ----------------
__device__ __forceinline__ void gsync(unsigned* bar){
    __syncthreads();
    if (threadIdx.x == 0){
        __threadfence();
        unsigned g = __hip_atomic_load(bar+1, __ATOMIC_RELAXED, __HIP_MEMORY_SCOPE_AGENT);
        unsigned a = __hip_atomic_fetch_add(bar, 1u, __ATOMIC_ACQ_REL, __HIP_MEMORY_SCOPE_AGENT);
        if (a == NBLK-1u){
            __hip_atomic_store(bar, 0u, __ATOMIC_RELAXED, __HIP_MEMORY_SCOPE_AGENT);
            __hip_atomic_store(bar+1, g+1u, __ATOMIC_RELEASE, __HIP_MEMORY_SCOPE_AGENT);
        } else {
            while (__hip_atomic_load(bar+1, __ATOMIC_ACQUIRE, __HIP_MEMORY_SCOPE_AGENT) == g){
                __builtin_amdgcn_s_sleep(1);
            }
        }
        __threadfence();
    }
    __syncthreads();
}

// --------- partial matmul: out[kc][16][outw] slice, 256 cols, K-chunk kc ----
// threads: cg = tid&63 (4 cols each), rg = tid>>6 (4 rows each)
__device__ __forceinline__ void mm_partial(
    const float* __restrict__ A, int ars, int aco,
    const float* __restrict__ W, int ldw,
    float* __restrict__ outP, int outw,
    int cbase, int kc,
    const float* __restrict__ bias1,
    float* __restrict__ Ash, int tid)
{
    const int k0 = kc*KC;
    for (int idx = tid; idx < 16*KC; idx += NTHR){
        int r = idx / KC, k = idx - r*KC;
        Ash[idx] = A[(size_t)r*ars + aco + k0 + k];
    }
    __syncthreads();
    const int cg = tid & 63, rg = tid >> 6;
    const int col = cbase + cg*4;
    const int r0 = rg*4;
    const float* a0 = Ash + (r0+0)*KC;
    const float* a1 = Ash + (r0+1)*KC;
    const float* a2 = Ash + (r0+2)*KC;
    const float* a3 = Ash + (r0+3)*KC;
    float4 c0={0,0,0,0}, c1={0,0,0,0}, c2={0,0,0,0}, c3={0,0,0,0};
    const float* Wc = W + (size_t)k0*ldw + col;
    #pragma unroll 4
    for (int k = 0; k < KC; ++k){
        const float4 w = *(const float4*)Wc; Wc += ldw;
        const float x0=a0[k], x1=a1[k], x2=a2[k], x3=a3[k];
        c0.x = fmaf(x0,w.x,c0.x); c0.y = fmaf(x0,w.y,c0.y); c0.z = fmaf(x0,w.z,c0.z); c0.w = fmaf(x0,w.w,c0.w);
        c1.x = fmaf(x1,w.x,c1.x); c1.y = fmaf(x1,w.y,c1.y); c1.z = fmaf(x1,w.z,c1.z); c1.w = fmaf(x1,w.w,c1.w);
        c2.x = fmaf(x2,w.x,c2.x); c2.y = fmaf(x2,w.y,c2.y); c2.z = fmaf(x2,w.z,c2.z); c2.w = fmaf(x2,w.w,c2.w);
        c3.x = fmaf(x3,w.x,c3.x); c3.y = fmaf(x3,w.y,c3.y); c3.z = fmaf(x3,w.z,c3.z); c3.w = fmaf(x3,w.w,c3.w);
    }
    if (kc == 0 && bias1){
        float4 bv = *(const float4*)(bias1 + col);
        c0.x+=bv.x; c0.y+=bv.y; c0.z+=bv.z; c0.w+=bv.w;
        c1.x+=bv.x; c1.y+=bv.y; c1.z+=bv.z; c1.w+=bv.w;
        c2.x+=bv.x; c2.y+=bv.y; c2.z+=bv.z; c2.w+=bv.w;
        c3.x+=bv.x; c3.y+=bv.y; c3.z+=bv.z; c3.w+=bv.w;
    }
    float* o = outP + ((size_t)(kc*16 + r0))*outw + col;
    *(float4*)(o)           = c0;
    *(float4*)(o +   outw)  = c1;
    *(float4*)(o + 2*outw)  = c2;
    *(float4*)(o + 3*outw)  = c3;
}

__device__ __forceinline__ float bsum4(float v, float* red, int tid){
    #pragma unroll
    for (int off = 32; off; off >>= 1) v += __shfl_xor(v, off);
    __syncthreads();
    if ((tid & 63) == 0) red[tid >> 6] = v;
    __syncthreads();
    return red[0]+red[1]+red[2]+red[3];
}

__global__ __launch_bounds__(NTHR) void coop_kernel(Params p)
{
    __shared__ float smem[6936];
    const int tid = threadIdx.x;
    const int bid = blockIdx.x;

    // ---- prologue: zero h,c; write mask tail of output ----
    {
        int g = bid*NTHR + tid;
        for (int i = g; i < 2*2*16*768; i += NBLK*NTHR) p.hbuf[i] = 0.f;
        if (g < 16*128) p.out[(size_t)16*128*768 + g] = p.mask_p[g];
    }
    gsync(p.bar);

    for (int t = 0; t < 128; ++t){
        for (int d = 0; d < 2; ++d){
            // =========== S1: matmuls off h / cur ===========
            if (bid < 30*NK){
                int kc = bid & (NK-1), cb = bid >> 3;
                const float* h_d = p.hbuf + (size_t)d*16*768;
                const float* curA; int ars, aco;
                if (d == 0){ curA = p.input_p; ars = 128*768; aco = t*768; }
                else       { curA = p.hbuf;   ars = 768;     aco = 0;     }
                if (cb < 3){
                    mm_partial(h_d, 768, 0, p.Wr + (size_t)d*768*768, 768,
                               p.sP, 768, cb*256, kc, p.b_att + d*768, smem, tid);
                } else if (cb < 6){
                    mm_partial(curA, ars, aco, p.Wp + (size_t)d*768*768, 768,
                               p.sP + (size_t)NK*16*768, 768, (cb-3)*256, kc, nullptr, smem, tid);
                } else if (cb < 18){
                    mm_partial(h_d, 768, 0, p.W_hh + (size_t)d*768*3072, 3072,
                               p.whP, 3072, (cb-6)*256, kc, nullptr, smem, tid);
                } else {
                    mm_partial(curA, ars, aco, p.W_ih + (size_t)d*1536*3072, 3072,
                               p.cwP, 3072, (cb-18)*256, kc, nullptr, smem, tid);
                }
            }
            gsync(p.bar);

            // =========== S2a: scores + exp ===========
            {
                int b = bid >> 4, sq0 = (bid & 15)*8;
                float* s_sh = smem;
                float* w_sh = smem + 768;
                for (int idx = tid; idx < 768; idx += NTHR){
                    float v = 0.f;
                    #pragma unroll
                    for (int q = 0; q < 2*NK; q++)
                        v += p.sP[((size_t)q*16 + b)*768 + idx];
                    s_sh[idx] = v;
                    w_sh[idx] = p.w_att[d*768 + idx];
                }
                __syncthreads();
                int grp = tid >> 5, l32 = tid & 31;
                int sq = sq0 + grp;
                const float* qrow = p.qWq + (size_t)((d*16 + b)*128 + sq)*768;
                float part = 0.f;
                #pragma unroll
                for (int i = 0; i < 6; i++){
                    int a = i*128 + l32*4;
                    float4 q  = *(const float4*)(qrow + a);
                    float4 s4 = *(const float4*)(s_sh + a);
                    float4 w4 = *(const float4*)(w_sh + a);
                    part += ftanh(q.x + s4.x)*w4.x + ftanh(q.y + s4.y)*w4.y
                          + ftanh(q.z + s4.z)*w4.z + ftanh(q.w + s4.w)*w4.w;
                }
                #pragma unroll
                for (int off = 16; off; off >>= 1) part += __shfl_xor(part, off, 32);
                if (l32 == 0){
                    float e = (p.mask_q[b*128 + sq] > 0.f) ? __expf(fminf(part, 30.f)) : 0.f;
                    p.escore[b*128 + sq] = e;
                }
            }
            gsync(p.bar);

            // =========== S2b: normalize + weighted ===========
            {
                int b = bid >> 4, cbase = (bid & 15)*48;
                float* e_sh = smem;           // 128
                float* part = smem + 132;     // 4*48
                if (tid < 128) e_sh[tid] = p.escore[b*128 + tid];
                __syncthreads();
                if (tid < 64){
                    float v = e_sh[tid] + e_sh[tid + 64];
                    #pragma unroll
                    for (int off = 32; off; off >>= 1) v += __shfl_xor(v, off);
                    if (tid == 0) e_sh[128] = 1.0f / v;
                }
                __syncthreads();
                float invd = e_sh[128];
                int c = tid % 48, ks = tid / 48;
                if (ks < 4){
                    float acc = 0.f;
                    const float* iq = p.input_q + ((size_t)b*128 + ks*32)*768 + cbase + c;
                    #pragma unroll 4
                    for (int j = 0; j < 32; j++) acc += e_sh[ks*32 + j]*iq[(size_t)j*768];
                    part[ks*48 + c] = acc;
                }
                __syncthreads();
                if (tid < 48){
                    float w = (part[tid] + part[48+tid] + part[96+tid] + part[144+tid]) * invd;
                    p.wghtd[b*768 + cbase + tid] = w;
                }
            }
            gsync(p.bar);

            // =========== S3: wi = weighted @ W_ih[d][768:1536] ===========
            if (bid < 12*NK){
                int kc = bid & (NK-1), cb = bid >> 3;
                mm_partial(p.wghtd, 768, 0,
                           p.W_ih + (size_t)d*1536*3072 + (size_t)768*3072, 3072,
                           p.wiP, 3072, cb*256, kc, nullptr, smem, tid);
            }
            gsync(p.bar);

            // =========== S4: LN + gates ===========
            if (bid < 16){
                const int b = bid;
                float* wi_sh = smem;
                float* wh_sh = smem + 3072;
                float* c_sh  = smem + 6144;
                float* red   = smem + 6928;
                const float mm = p.mask_p[b*128 + t];
                const float* gi = p.ln_i_g + d*3072; const float* bi = p.ln_i_b + d*3072;
                const float* gh = p.ln_h_g + d*3072; const float* bh = p.ln_h_b + d*3072;
                const float* gc = p.ln_c_g + d*768;  const float* bc = p.ln_c_b + d*768;
                const float* bias_d = p.bias + d*3072;

                float swi=0,qwi=0,swh=0,qwh=0;
                for (int j = tid; j < 3072; j += NTHR){
                    float a = 0.f, h = 0.f;
                    #pragma unroll
                    for (int q = 0; q < NK; q++){
                        a += p.wiP[((size_t)q*16 + b)*3072 + j];
                        h += p.whP[((size_t)q*16 + b)*3072 + j];
                        a += p.cwP[((size_t)q*16 + b)*3072 + j];
                    }
                    wi_sh[j] = a; wh_sh[j] = h;
                    swi += a; qwi += a*a; swh += h; qwh += h*h;
                }
                swi = bsum4(swi, red, tid);
                qwi = bsum4(qwi, red, tid);
                swh = bsum4(swh, red, tid);
                qwh = bsum4(qwh, red, tid);
                float mi = swi/3072.f, vi = fmaxf((qwi - 3072.f*mi*mi)/3071.f, 0.f);
                float mh = swh/3072.f, vh = fmaxf((qwh - 3072.f*mh*mh)/3071.f, 0.f);
                float ivi = 1.f/(sqrtf(vi + 1e-6f) + 1e-6f);
                float ivh = 1.f/(sqrtf(vh + 1e-6f) + 1e-6f);

                for (int j = tid; j < 3072; j += NTHR){
                    float pre = mm*(gi[j]*(wi_sh[j]-mi)*ivi + bi[j])
                              + mm*(gh[j]*(wh_sh[j]-mh)*ivh + bh[j])
                              + bias_d[j];
                    wi_sh[j] = pre;
                }
                __syncthreads();

                float sc=0,qc=0;
                for (int u = tid; u < 768; u += NTHR){
                    float f  = wi_sh[u];
                    float ig = wi_sh[768 + u];
                    float g  = wi_sh[2304 + u];
                    float c_old = p.cbuf[(size_t)(d*16+b)*768 + u];
                    float c1 = fsigmoid(f)*c_old + fsigmoid(ig)*ftanh(g);
                    c1 = c1*mm + c_old*(1.f - mm);
                    p.cbuf[(size_t)(d*16+b)*768 + u] = c1;
                    c_sh[u] = c1;
                    sc += c1; qc += c1*c1;
                }
                sc = bsum4(sc, red, tid);
                qc = bsum4(qc, red, tid);
                float mc = sc/768.f, vc = fmaxf((qc - 768.f*mc*mc)/767.f, 0.f);
                float ivc = 1.f/(sqrtf(vc + 1e-6f) + 1e-6f);

                for (int u = tid; u < 768; u += NTHR){
                    float o = wi_sh[1536 + u];
                    float lnc = (gc[u]*(c_sh[u]-mc)*ivc + bc[u])*mm;
                    float h1 = fsigmoid(o)*ftanh(lnc);
                    float h_old = p.hbuf[(size_t)(d*16+b)*768 + u];
                    h1 = h1*mm + h_old*(1.f - mm);
                    p.hbuf[(size_t)(d*16+b)*768 + u] = h1;
                    if (d == 1) p.out[((size_t)b*128 + t)*768 + u] = h1;
                }
            }
            gsync(p.bar);
        }
    }
}

// ---------- precompute GEMM for qWq (same as validated round-0 kernel) ----------
__global__ __launch_bounds__(256) void k_mm_pre(
    const float* __restrict__ Ain, const float* __restrict__ W,
    float* __restrict__ C, int ldw, int ncols)
{
    __shared__ float Ash[16][772];
    int rowbase = blockIdx.y*16;
    for (int r = 0; r < 16; r++)
        for (int i = threadIdx.x; i < 768; i += 256)
            Ash[r][i] = Ain[(size_t)(rowbase + r)*768 + i];
    __syncthreads();
    int lane = threadIdx.x & 63;
    int colq = lane & 15, rsub = lane >> 4, wq = threadIdx.x >> 6;
    int r = wq*4 + rsub;
    int col = blockIdx.x*64 + colq*4;
    float4 acc = {0.f,0.f,0.f,0.f};
    const float* Wc = W + col;
    for (int k = 0; k < 768; k += 4){
        float4 a4 = *(const float4*)&Ash[r][k];
        float4 w0 = *(const float4*)(Wc + (size_t)(k+0)*ldw);
        float4 w1 = *(const float4*)(Wc + (size_t)(k+1)*ldw);
        float4 w2 = *(const float4*)(Wc + (size_t)(k+2)*ldw);
        float4 w3 = *(const float4*)(Wc + (size_t)(k+3)*ldw);
        acc.x += a4.x*w0.x + a4.y*w1.x + a4.z*w2.x + a4.w*w3.x;
        acc.y += a4.x*w0.y + a4.y*w1.y + a4.z*w2.y + a4.w*w3.y;
        acc.z += a4.x*w0.z + a4.y*w1.z + a4.z*w2.z + a4.w*w3.z;
        acc.w += a4.x*w0.w + a4.y*w1.w + a4.z*w2.w + a4.w*w3.w;
    }
    *(float4*)(C + (size_t)(rowbase + r)*ncols + col) = acc;
}

extern "C" void kernel_launch(void* const* d_in, const int* in_sizes, int n_in,
                              void* d_out, int out_size, void* d_ws, size_t ws_size,
                              hipStream_t stream)
{
    (void)in_sizes; (void)n_in; (void)out_size; (void)ws_size;
    Params P;
    P.input_p = (const float*)d_in[0];
    P.mask_p  = (const float*)d_in[1];
    P.input_q = (const float*)d_in[2];
    P.mask_q  = (const float*)d_in[3];
    P.W_ih    = (const float*)d_in[4];
    P.W_hh    = (const float*)d_in[5];
    P.bias    = (const float*)d_in[6];
    P.ln_i_g  = (const float*)d_in[7];
    P.ln_i_b  = (const float*)d_in[8];
    P.ln_h_g  = (const float*)d_in[9];
    P.ln_h_b  = (const float*)d_in[10];
    P.ln_c_g  = (const float*)d_in[11];
    P.ln_c_b  = (const float*)d_in[12];
    P.Wq      = (const float*)d_in[13];
    P.Wp      = (const float*)d_in[14];
    P.Wr      = (const float*)d_in[15];
    P.w_att   = (const float*)d_in[16];
    P.b_att   = (const float*)d_in[17];
    P.out     = (float*)d_out;

    float* ws = (float*)d_ws;
    size_t off = 0;
    P.qWq    = ws + off; off += (size_t)2*16*128*768;
    P.hbuf   = ws + off; off += (size_t)2*16*768;
    P.cbuf   = ws + off; off += (size_t)2*16*768;
    P.sP     = ws + off; off += (size_t)2*NK*16*768;
    P.whP    = ws + off; off += (size_t)NK*16*3072;
    P.cwP    = ws + off; off += (size_t)NK*16*3072;
    P.wiP    = ws + off; off += (size_t)NK*16*3072;
    P.escore = ws + off; off += 2048;
    P.wghtd  = ws + off; off += (size_t)16*768;
    P.bar    = (unsigned*)(ws + off); off += 16;

    hipMemsetAsync((void*)P.bar, 0, 2*sizeof(unsigned), stream);
    k_mm_pre<<<dim3(12,128), 256, 0, stream>>>(P.input_q, P.Wq, P.qWq, 768, 768);
    k_mm_pre<<<dim3(12,128), 256, 0, stream>>>(P.input_q, P.Wq + (size_t)768*768,
                                               P.qWq + (size_t)2048*768, 768, 768);
    void* args[] = { &P };
    hipLaunchCooperativeKernel((void*)coop_kernel, dim3(NBLK), dim3(NTHR), args, 0, stream);
}

// Round 5
// 23615.120 us; speedup vs baseline: 3.0835x; 3.0835x over previous
//
#include <hip/hip_runtime.h>
#include <math.h>

#define NBLK 256
#define NTHR 256

typedef float f32x4 __attribute__((ext_vector_type(4)));

// ---------------- coherent (cross-XCD, L2-bypass) access helpers ----------------
// 64-bit relaxed agent-scope atomics: compiler emits coherent (sc1) loads/stores
// and manages all waitcnts. Used ONLY for mutable intermediates; weights and all
// read-only tensors use normal cached loads so they stay L2-resident.
__device__ __forceinline__ float2 ld2a(const float* p){
    unsigned long long u = __hip_atomic_load((const unsigned long long*)p,
                                             __ATOMIC_RELAXED, __HIP_MEMORY_SCOPE_AGENT);
    float2 r;
    r.x = __uint_as_float((unsigned)u);
    r.y = __uint_as_float((unsigned)(u >> 32));
    return r;
}
__device__ __forceinline__ void st2a(float* p, float a, float b){
    unsigned long long u = (unsigned long long)__float_as_uint(a)
                         | ((unsigned long long)__float_as_uint(b) << 32);
    __hip_atomic_store((unsigned long long*)p, u,
                       __ATOMIC_RELAXED, __HIP_MEMORY_SCOPE_AGENT);
}

__device__ __forceinline__ float fsigmoid(float x){ return 1.0f/(1.0f + __expf(-x)); }
__device__ __forceinline__ float ftanh(float x){
    float e = __expf(2.0f*x);          // inf-safe
    return 1.0f - 2.0f/(e + 1.0f);
}
__device__ __forceinline__ float dot4(f32x4 a, f32x4 b){
    return a.x*b.x + a.y*b.y + a.z*b.z + a.w*b.w;
}

struct Params {
    const float* input_p; const float* mask_p; const float* input_q; const float* mask_q;
    const float* W_ih; const float* W_hh; const float* bias;
    const float* ln_i_g; const float* ln_i_b; const float* ln_h_g; const float* ln_h_b;
    const float* ln_c_g; const float* ln_c_b;
    const float* Wq; const float* Wp; const float* Wr; const float* w_att; const float* b_att;
    float* out;
    float* qWq;    // [2][16][128][768] read-only in coop
    float* iqT;    // [16][768][128]    read-only in coop
    float* h;      // [2][16][768] coherent
    float* c;      // [2][16][768] coherent (contiguous after h)
    float* sP;     // [16][16][768] coherent (copies 0-7: h@Wr ; 8-15: cur@Wp)
    float* whP;    // [8][16][3072] coherent
    float* cwP;    // [8][16][3072] coherent
    float* wiP;    // [8][16][3072] coherent
    float* whR;    // [16][3072] coherent
    float* cwR;    // [16][3072] coherent
    float* wghtd;  // [16][768] coherent
    unsigned* bar; // gen@0, root@32, leaf i @ 128+32i
};

// ------------- monotonic tree barrier: relaxed atomics, RELEASE on gen -------------
// Bounded spin: if relaxed polling were ever non-read-through, the periodic
// ACQUIRE load forces freshness (and forward progress) at ~1 inv per fallback.
__device__ __forceinline__ void gsync(unsigned* bar, int bid, unsigned n){
    __syncthreads();                       // drains this block's stores (vmcnt 0)
    if (threadIdx.x == 0){
        unsigned* leaf = bar + 128 + (bid >> 4)*32;
        unsigned old = __hip_atomic_fetch_add(leaf, 1u, __ATOMIC_RELAXED, __HIP_MEMORY_SCOPE_AGENT);
        if ((old & 15u) == 15u){
            unsigned rold = __hip_atomic_fetch_add(bar + 32, 1u, __ATOMIC_RELAXED, __HIP_MEMORY_SCOPE_AGENT);
            if ((rold & 15u) == 15u){
                __hip_atomic_store(bar, n + 1u, __ATOMIC_RELEASE, __HIP_MEMORY_SCOPE_AGENT);
            }
        }
        int spins = 0;
        while (__hip_atomic_load(bar, __ATOMIC_RELAXED, __HIP_MEMORY_SCOPE_AGENT) < n + 1u){
            __builtin_amdgcn_s_sleep(4);
            if (++spins > 1024){
                (void)__hip_atomic_load(bar, __ATOMIC_ACQUIRE, __HIP_MEMORY_SCOPE_AGENT);
                spins = 0;
            }
        }
    }
    __syncthreads();
}

// tile matmul: C[16 x 256cols] partial over k0..k0+95; A staged coherent to LDS;
// W via normal cached loads (stays in L2).
__device__ __forceinline__ void mm96(
    const float* Aptr, int ars, int aco, int k0,
    const float* Wmat, int N, float* outP, int cbase,
    float* Ash, int tid)
{
    // stage 16 rows x 96 cols = 768 f2 chunks; 256 threads x 3
    #pragma unroll
    for (int rep = 0; rep < 3; rep++){
        int i2 = tid + rep*256;                 // f2 index < 768
        int r = i2 / 48, kk = (i2 % 48)*2;      // 48 f2 per row
        float2 v = ld2a(Aptr + (size_t)r*ars + aco + k0 + kk);
        Ash[r*96 + kk]     = v.x;
        Ash[r*96 + kk + 1] = v.y;
    }
    __syncthreads();
    int cg = tid & 63, rg = tid >> 6;
    int col = cbase + cg*4;
    int r0 = rg*4;
    f32x4 acc0 = {0,0,0,0}, acc1 = {0,0,0,0}, acc2 = {0,0,0,0}, acc3 = {0,0,0,0};
    const float* Wc = Wmat + (size_t)k0*N + col;
    #pragma unroll 4
    for (int k = 0; k < 96; k += 4){
        f32x4 a0 = *(const f32x4*)&Ash[(r0+0)*96 + k];
        f32x4 a1 = *(const f32x4*)&Ash[(r0+1)*96 + k];
        f32x4 a2 = *(const f32x4*)&Ash[(r0+2)*96 + k];
        f32x4 a3 = *(const f32x4*)&Ash[(r0+3)*96 + k];
        f32x4 w0 = *(const f32x4*)(Wc + (size_t)(k+0)*N);
        f32x4 w1 = *(const f32x4*)(Wc + (size_t)(k+1)*N);
        f32x4 w2 = *(const f32x4*)(Wc + (size_t)(k+2)*N);
        f32x4 w3 = *(const f32x4*)(Wc + (size_t)(k+3)*N);
        acc0 += a0.x*w0 + a0.y*w1 + a0.z*w2 + a0.w*w3;
        acc1 += a1.x*w0 + a1.y*w1 + a1.z*w2 + a1.w*w3;
        acc2 += a2.x*w0 + a2.y*w1 + a2.z*w2 + a2.w*w3;
        acc3 += a3.x*w0 + a3.y*w1 + a3.z*w2 + a3.w*w3;
    }
    float* o = outP + (size_t)r0*N + col;
    st2a(o,                 acc0.x, acc0.y); st2a(o + 2,                 acc0.z, acc0.w);
    st2a(o + (size_t)N,     acc1.x, acc1.y); st2a(o + (size_t)N + 2,     acc1.z, acc1.w);
    st2a(o + 2*(size_t)N,   acc2.x, acc2.y); st2a(o + 2*(size_t)N + 2,   acc2.z, acc2.w);
    st2a(o + 3*(size_t)N,   acc3.x, acc3.y); st2a(o + 3*(size_t)N + 2,   acc3.z, acc3.w);
    __syncthreads();   // Ash reuse safety
}

__device__ __forceinline__ float bsum4(float v, float* red, int tid){
    #pragma unroll
    for (int off = 32; off; off >>= 1) v += __shfl_xor(v, off);
    __syncthreads();
    if ((tid & 63) == 0) red[tid >> 6] = v;
    __syncthreads();
    float s = red[0]+red[1]+red[2]+red[3];
    __syncthreads();
    return s;
}

__global__ __launch_bounds__(NTHR) void coop_kernel(Params p)
{
    __shared__ float smem[6936];
    const int tid = threadIdx.x;
    const int bid = blockIdx.x;
    unsigned n = 0;

    // prologue: zero h,c (coherent); copy mask tail of output (plain)
    {
        int gid = bid*NTHR + tid;
        if (gid < 24576) st2a(p.h + gid*2, 0.f, 0.f);   // h then c, contiguous
        if (gid < 2048)  p.out[(size_t)16*128*768 + gid] = p.mask_p[gid];
    }
    gsync(p.bar, bid, n); n++;

    for (int t = 0; t < 128; ++t){
        for (int d = 0; d < 2; ++d){
            const float* h_d = p.h + (size_t)d*12288;
            const float* curA; int ars, aco;
            if (d == 0){ curA = p.input_p; ars = 98304; aco = t*768; }
            else       { curA = p.h;      ars = 768;   aco = 0;     }

            // ================= S1: h/cur matmuls (240 blocks) =================
            if (bid < 240){
                int tile = bid >> 3, kc = bid & 7;
                int k0 = kc*96;
                if (tile < 3){
                    mm96(h_d, 768, 0, k0, p.Wr + (size_t)d*589824, 768,
                         p.sP + (size_t)kc*12288, tile*256, smem, tid);
                } else if (tile < 6){
                    mm96(curA, ars, aco, k0, p.Wp + (size_t)d*589824, 768,
                         p.sP + (size_t)(8+kc)*12288, (tile-3)*256, smem, tid);
                } else if (tile < 18){
                    mm96(h_d, 768, 0, k0, p.W_hh + (size_t)d*2359296, 3072,
                         p.whP + (size_t)kc*49152, (tile-6)*256, smem, tid);
                } else {
                    mm96(curA, ars, aco, k0, p.W_ih + (size_t)d*4718592, 3072,
                         p.cwP + (size_t)kc*49152, (tile-18)*256, smem, tid);
                }
            }
            gsync(p.bar, bid, n); n++;

            // ================= S2: fused attention (16 blocks) =================
            if (bid < 16){
                const int b = bid;
                float* s_sh  = smem;          // 768
                float* wa_sh = smem + 768;    // 768
                float* e_sh  = smem + 1536;   // 132
                if (tid < 192){
                    f32x4 acc;
                    acc = *(const f32x4*)(p.b_att + d*768 + tid*4);   // plain (read-only)
                    #pragma unroll
                    for (int cp = 0; cp < 16; cp++){
                        const float* src = p.sP + (size_t)cp*12288 + b*768 + tid*4;
                        float2 u0 = ld2a(src);
                        float2 u1 = ld2a(src + 2);
                        acc.x += u0.x; acc.y += u0.y; acc.z += u1.x; acc.w += u1.y;
                    }
                    *(f32x4*)&s_sh[tid*4] = acc;
                } else {
                    int i0 = tid - 192;       // 64 threads x 3 f4 of w_att
                    for (int r = 0; r < 3; r++){
                        int i = i0 + r*64;
                        *(f32x4*)&wa_sh[i*4] = *(const f32x4*)(p.w_att + d*768 + i*4);
                    }
                }
                __syncthreads();
                // scores: 2 threads per sq
                {
                    int sq = tid >> 1, half = tid & 1;
                    const float* qrow = p.qWq + ((size_t)(d*2048 + b*128 + sq))*768 + half*384;
                    const float* ss = s_sh + half*384;
                    const float* ww = wa_sh + half*384;
                    float part = 0.f;
                    #pragma unroll 4
                    for (int i = 0; i < 96; i++){
                        f32x4 q  = *(const f32x4*)(qrow + i*4);
                        f32x4 s4 = *(const f32x4*)(ss + i*4);
                        f32x4 w4 = *(const f32x4*)(ww + i*4);
                        part += ftanh(q.x + s4.x)*w4.x + ftanh(q.y + s4.y)*w4.y
                              + ftanh(q.z + s4.z)*w4.z + ftanh(q.w + s4.w)*w4.w;
                    }
                    part += __shfl_xor(part, 1);
                    if (half == 0){
                        e_sh[sq] = (p.mask_q[b*128 + sq] > 0.f) ? __expf(part) : 0.f;
                    }
                }
                __syncthreads();
                if (tid < 64){
                    float v = e_sh[tid] + e_sh[tid + 64];
                    #pragma unroll
                    for (int off = 32; off; off >>= 1) v += __shfl_xor(v, off);
                    if (tid == 0) e_sh[128] = 1.0f / v;
                }
                __syncthreads();
                float inv = e_sh[128];
                // weighted via transposed input_q (plain loads): 2 cols per task
                for (int idx = tid; idx < 384; idx += NTHR){
                    int cc = idx*2;
                    const float* ip = p.iqT + ((size_t)b*768 + cc)*128;
                    float a0 = 0.f, a1 = 0.f;
                    #pragma unroll 8
                    for (int j = 0; j < 32; j++){
                        f32x4 q0 = *(const f32x4*)(ip + j*4);
                        f32x4 q1 = *(const f32x4*)(ip + 128 + j*4);
                        f32x4 e4 = *(const f32x4*)&e_sh[j*4];
                        a0 += dot4(q0, e4);
                        a1 += dot4(q1, e4);
                    }
                    st2a(p.wghtd + b*768 + cc, a0*inv, a1*inv);
                }
            }
            gsync(p.bar, bid, n); n++;

            // ============ S3: wi matmul (96 blocks) + wh/cw reduce (160) ============
            if (bid < 96){
                int tile = bid >> 3, kc = bid & 7;
                mm96(p.wghtd, 768, 0, kc*96,
                     p.W_ih + (size_t)d*4718592 + (size_t)768*3072, 3072,
                     p.wiP + (size_t)kc*49152, tile*256, smem, tid);
            } else {
                int gid = (bid - 96)*NTHR + tid;
                if (gid < 24576){
                    int which = gid / 12288;
                    int i4 = gid % 12288;
                    const float* src = which ? p.cwP : p.whP;
                    float* dst = which ? p.cwR : p.whR;
                    float2 a0 = {0.f,0.f}, a1 = {0.f,0.f};
                    #pragma unroll
                    for (int cp = 0; cp < 8; cp++){
                        const float* s0 = src + (size_t)cp*49152 + i4*4;
                        float2 u0 = ld2a(s0);
                        float2 u1 = ld2a(s0 + 2);
                        a0.x += u0.x; a0.y += u0.y; a1.x += u1.x; a1.y += u1.y;
                    }
                    st2a(dst + i4*4,     a0.x, a0.y);
                    st2a(dst + i4*4 + 2, a1.x, a1.y);
                }
            }
            gsync(p.bar, bid, n); n++;

            // ================= S4: LN + gates (16 blocks) =================
            if (bid < 16){
                const int b = bid;
                float* wi_sh = smem;           // 3072
                float* wh_sh = smem + 3072;    // 3072
                float* c_sh  = smem + 6144;    // 768
                float* red   = smem + 6928;    // 4
                const float mm = p.mask_p[b*128 + t];
                const float* gi = p.ln_i_g + d*3072; const float* bi = p.ln_i_b + d*3072;
                const float* gh = p.ln_h_g + d*3072; const float* bh = p.ln_h_b + d*3072;
                const float* gc = p.ln_c_g + d*768;  const float* bc = p.ln_c_b + d*768;
                const float* bias_d = p.bias + d*3072;

                float swi=0,qwi=0,swh=0,qwh=0;
                #pragma unroll
                for (int rep = 0; rep < 3; rep++){
                    int j4 = tid + rep*256;            // f4 index < 768
                    int base = b*3072 + j4*4;
                    f32x4 a = {0,0,0,0};
                    #pragma unroll
                    for (int cp = 0; cp < 8; cp++){
                        const float* s0 = p.wiP + (size_t)cp*49152 + base;
                        float2 u0 = ld2a(s0);
                        float2 u1 = ld2a(s0 + 2);
                        a.x += u0.x; a.y += u0.y; a.z += u1.x; a.w += u1.y;
                    }
                    float2 cw0 = ld2a(p.cwR + base), cw1 = ld2a(p.cwR + base + 2);
                    float2 wh0 = ld2a(p.whR + base), wh1 = ld2a(p.whR + base + 2);
                    a.x += cw0.x; a.y += cw0.y; a.z += cw1.x; a.w += cw1.y;
                    f32x4 hvec = { wh0.x, wh0.y, wh1.x, wh1.y };
                    *(f32x4*)&wi_sh[j4*4] = a;
                    *(f32x4*)&wh_sh[j4*4] = hvec;
                    swi += a.x+a.y+a.z+a.w;
                    qwi += dot4(a,a);
                    swh += hvec.x+hvec.y+hvec.z+hvec.w;
                    qwh += dot4(hvec,hvec);
                }
                swi = bsum4(swi, red, tid);
                qwi = bsum4(qwi, red, tid);
                swh = bsum4(swh, red, tid);
                qwh = bsum4(qwh, red, tid);
                float mi = swi/3072.f, vi = fmaxf((qwi - 3072.f*mi*mi)/3071.f, 0.f);
                float mh = swh/3072.f, vh = fmaxf((qwh - 3072.f*mh*mh)/3071.f, 0.f);
                float ivi = 1.f/(sqrtf(vi + 1e-6f) + 1e-6f);
                float ivh = 1.f/(sqrtf(vh + 1e-6f) + 1e-6f);

                for (int j = tid; j < 3072; j += NTHR){
                    float pre = mm*(gi[j]*(wi_sh[j]-mi)*ivi + bi[j])
                              + mm*(gh[j]*(wh_sh[j]-mh)*ivh + bh[j])
                              + bias_d[j];
                    wi_sh[j] = pre;
                }
                __syncthreads();

                float sc=0,qc=0;
                for (int idx = tid; idx < 384; idx += NTHR){
                    int u = idx*2;
                    float2 c_old = ld2a(p.c + (size_t)d*12288 + b*768 + u);
                    float f0  = wi_sh[u],        f1  = wi_sh[u+1];
                    float i0  = wi_sh[768+u],    i1  = wi_sh[768+u+1];
                    float g0  = wi_sh[2304+u],   g1  = wi_sh[2304+u+1];
                    float c10 = fsigmoid(f0)*c_old.x + fsigmoid(i0)*ftanh(g0);
                    float c11 = fsigmoid(f1)*c_old.y + fsigmoid(i1)*ftanh(g1);
                    c10 = c10*mm + c_old.x*(1.f - mm);
                    c11 = c11*mm + c_old.y*(1.f - mm);
                    st2a(p.c + (size_t)d*12288 + b*768 + u, c10, c11);
                    c_sh[u] = c10; c_sh[u+1] = c11;
                    sc += c10 + c11; qc += c10*c10 + c11*c11;
                }
                sc = bsum4(sc, red, tid);
                qc = bsum4(qc, red, tid);
                float mc = sc/768.f, vc = fmaxf((qc - 768.f*mc*mc)/767.f, 0.f);
                float ivc = 1.f/(sqrtf(vc + 1e-6f) + 1e-6f);

                for (int idx = tid; idx < 384; idx += NTHR){
                    int u = idx*2;
                    float2 h_old = ld2a(p.h + (size_t)d*12288 + b*768 + u);
                    float o0 = wi_sh[1536+u], o1 = wi_sh[1536+u+1];
                    float l0 = (gc[u]*(c_sh[u]-mc)*ivc + bc[u])*mm;
                    float l1 = (gc[u+1]*(c_sh[u+1]-mc)*ivc + bc[u+1])*mm;
                    float h10 = fsigmoid(o0)*ftanh(l0);
                    float h11 = fsigmoid(o1)*ftanh(l1);
                    h10 = h10*mm + h_old.x*(1.f - mm);
                    h11 = h11*mm + h_old.y*(1.f - mm);
                    st2a(p.h + (size_t)d*12288 + b*768 + u, h10, h11);
                    if (d == 1){
                        float2 ov = { h10, h11 };
                        *(float2*)(p.out + ((size_t)b*128 + t)*768 + u) = ov;
                    }
                }
            }
            gsync(p.bar, bid, n); n++;
        }
    }
}

// ---------- precompute GEMM for qWq (validated round-0/1 kernel) ----------
__global__ __launch_bounds__(256) void k_mm_pre(
    const float* __restrict__ Ain, const float* __restrict__ W,
    float* __restrict__ C, int ldw, int ncols)
{
    __shared__ float Ash[16][772];
    int rowbase = blockIdx.y*16;
    for (int r = 0; r < 16; r++)
        for (int i = threadIdx.x; i < 768; i += 256)
            Ash[r][i] = Ain[(size_t)(rowbase + r)*768 + i];
    __syncthreads();
    int lane = threadIdx.x & 63;
    int colq = lane & 15, rsub = lane >> 4, wq = threadIdx.x >> 6;
    int r = wq*4 + rsub;
    int col = blockIdx.x*64 + colq*4;
    float4 acc = {0.f,0.f,0.f,0.f};
    const float* Wc = W + col;
    for (int k = 0; k < 768; k += 4){
        float4 a4 = *(const float4*)&Ash[r][k];
        float4 w0 = *(const float4*)(Wc + (size_t)(k+0)*ldw);
        float4 w1 = *(const float4*)(Wc + (size_t)(k+1)*ldw);
        float4 w2 = *(const float4*)(Wc + (size_t)(k+2)*ldw);
        float4 w3 = *(const float4*)(Wc + (size_t)(k+3)*ldw);
        acc.x += a4.x*w0.x + a4.y*w1.x + a4.z*w2.x + a4.w*w3.x;
        acc.y += a4.x*w0.y + a4.y*w1.y + a4.z*w2.y + a4.w*w3.y;
        acc.z += a4.x*w0.z + a4.y*w1.z + a4.z*w2.z + a4.w*w3.z;
        acc.w += a4.x*w0.w + a4.y*w1.w + a4.z*w2.w + a4.w*w3.w;
    }
    *(float4*)(C + (size_t)(rowbase + r)*ncols + col) = acc;
}

// ---------- transpose input_q -> iqT[b][c][sq] ----------
__global__ __launch_bounds__(256) void k_transq(
    const float* __restrict__ iq, float* __restrict__ iqT)
{
    __shared__ float Tsh[32][136];
    int c0 = blockIdx.x*32, b = blockIdx.y;
    for (int rep = 0; rep < 4; rep++){
        int idx = threadIdx.x + rep*256;
        int sq = idx >> 3, cq = idx & 7;
        float4 v = *(const float4*)(iq + ((size_t)b*128 + sq)*768 + c0 + cq*4);
        Tsh[cq*4+0][sq] = v.x;
        Tsh[cq*4+1][sq] = v.y;
        Tsh[cq*4+2][sq] = v.z;
        Tsh[cq*4+3][sq] = v.w;
    }
    __syncthreads();
    for (int rep = 0; rep < 4; rep++){
        int idx = threadIdx.x + rep*256;
        int cl = idx >> 5, sq4 = (idx & 31)*4;
        float4 v = *(const float4*)&Tsh[cl][sq4];
        *(float4*)(iqT + ((size_t)b*768 + c0 + cl)*128 + sq4) = v;
    }
}

extern "C" void kernel_launch(void* const* d_in, const int* in_sizes, int n_in,
                              void* d_out, int out_size, void* d_ws, size_t ws_size,
                              hipStream_t stream)
{
    (void)in_sizes; (void)n_in; (void)out_size; (void)ws_size;
    Params P;
    P.input_p = (const float*)d_in[0];
    P.mask_p  = (const float*)d_in[1];
    P.input_q = (const float*)d_in[2];
    P.mask_q  = (const float*)d_in[3];
    P.W_ih    = (const float*)d_in[4];
    P.W_hh    = (const float*)d_in[5];
    P.bias    = (const float*)d_in[6];
    P.ln_i_g  = (const float*)d_in[7];
    P.ln_i_b  = (const float*)d_in[8];
    P.ln_h_g  = (const float*)d_in[9];
    P.ln_h_b  = (const float*)d_in[10];
    P.ln_c_g  = (const float*)d_in[11];
    P.ln_c_b  = (const float*)d_in[12];
    P.Wq      = (const float*)d_in[13];
    P.Wp      = (const float*)d_in[14];
    P.Wr      = (const float*)d_in[15];
    P.w_att   = (const float*)d_in[16];
    P.b_att   = (const float*)d_in[17];
    P.out     = (float*)d_out;

    float* ws = (float*)d_ws;
    size_t off = 0;
    P.qWq   = ws + off; off += (size_t)2*16*128*768;
    P.iqT   = ws + off; off += (size_t)16*768*128;
    P.h     = ws + off; off += 24576;
    P.c     = ws + off; off += 24576;
    P.sP    = ws + off; off += (size_t)16*16*768;
    P.whP   = ws + off; off += (size_t)8*16*3072;
    P.cwP   = ws + off; off += (size_t)8*16*3072;
    P.wiP   = ws + off; off += (size_t)8*16*3072;
    P.whR   = ws + off; off += 49152;
    P.cwR   = ws + off; off += 49152;
    P.wghtd = ws + off; off += 12288;
    P.bar   = (unsigned*)(ws + off); off += 2048;

    hipMemsetAsync((void*)P.bar, 0, 2048*sizeof(unsigned), stream);
    k_mm_pre<<<dim3(12,128), 256, 0, stream>>>(P.input_q, P.Wq, P.qWq, 768, 768);
    k_mm_pre<<<dim3(12,128), 256, 0, stream>>>(P.input_q, P.Wq + (size_t)589824,
                                               P.qWq + (size_t)2048*768, 768, 768);
    k_transq<<<dim3(24,16), 256, 0, stream>>>(P.input_q, P.iqT);
    // Plain (non-cooperative) launch: 256 blocks x 256 threads on a 256-CU chip
    // with 28KB LDS is guaranteed co-resident; the cooperative API's silent
    // rejection was the prime suspect for R3/R4's "kernel never ran" signature.
    coop_kernel<<<dim3(NBLK), dim3(NTHR), 0, stream>>>(P);
}

// Round 7
// 17594.118 us; speedup vs baseline: 4.1387x; 1.3422x over previous
//
#include <hip/hip_runtime.h>
#include <math.h>

#define NBLK 512
#define NTHR 256

typedef float f32x4 __attribute__((ext_vector_type(4)));

// ---------------- coherent (cross-XCD, L2-bypass) access helpers ----------------
__device__ __forceinline__ float2 ld2a(const float* p){
    unsigned long long u = __hip_atomic_load((const unsigned long long*)p,
                                             __ATOMIC_RELAXED, __HIP_MEMORY_SCOPE_AGENT);
    float2 r;
    r.x = __uint_as_float((unsigned)u);
    r.y = __uint_as_float((unsigned)(u >> 32));
    return r;
}
__device__ __forceinline__ void st2a(float* p, float a, float b){
    unsigned long long u = (unsigned long long)__float_as_uint(a)
                         | ((unsigned long long)__float_as_uint(b) << 32);
    __hip_atomic_store((unsigned long long*)p, u,
                       __ATOMIC_RELAXED, __HIP_MEMORY_SCOPE_AGENT);
}
__device__ __forceinline__ float ld1a(const float* p){
    unsigned u = __hip_atomic_load((const unsigned*)p, __ATOMIC_RELAXED, __HIP_MEMORY_SCOPE_AGENT);
    return __uint_as_float(u);
}
__device__ __forceinline__ void st1a(float* p, float v){
    __hip_atomic_store((unsigned*)p, __float_as_uint(v), __ATOMIC_RELAXED, __HIP_MEMORY_SCOPE_AGENT);
}

__device__ __forceinline__ float fsigmoid(float x){ return 1.0f/(1.0f + __expf(-x)); }
__device__ __forceinline__ float ftanh(float x){
    float e = __expf(2.0f*x);          // inf-safe
    return 1.0f - 2.0f/(e + 1.0f);
}
__device__ __forceinline__ float dot4(f32x4 a, f32x4 b){
    return a.x*b.x + a.y*b.y + a.z*b.z + a.w*b.w;
}

struct Params {
    const float* input_p; const float* mask_p; const float* input_q; const float* mask_q;
    const float* W_ih; const float* W_hh; const float* bias;
    const float* ln_i_g; const float* ln_i_b; const float* ln_h_g; const float* ln_h_b;
    const float* ln_c_g; const float* ln_c_b;
    const float* Wq; const float* Wp; const float* Wr; const float* w_att; const float* b_att;
    float* out;
    float* qWq;    // [2][2048][768] f32, read-only in coop
    float* iqT;    // [16][768][128] f32, read-only
    float* pWp0;   // [b*128+t][768]  = input_p @ Wp[0], read-only
    float* pWih0;  // [b*128+t][3072] = input_p @ W_ih[0][:768], read-only
    float* h;      // [2][16][768] coherent
    float* c;      // coherent (contiguous after h)
    float* sP;     // [16][16][768] coherent (0-7: h@Wr ; 8-15: cur@Wp d=1)
    float* whP;    // [8][16][3072]
    float* cwP;    // [8][16][3072]
    float* wiP;    // [8][16][3072]
    float* whR;    // [16][3072]
    float* cwR;    // [16][3072]
    float* wghtd;  // [16][768]
    float* escore; // [16][128]
    unsigned* bar;
};

// ------------- monotonic tree barrier (512 blocks = 32 leaves x 16) -------------
__device__ __forceinline__ void gsync(unsigned* bar, int bid, unsigned n){
    __syncthreads();
    if (threadIdx.x == 0){
        unsigned* leaf = bar + 128 + (bid >> 4)*32;
        unsigned old = __hip_atomic_fetch_add(leaf, 1u, __ATOMIC_RELAXED, __HIP_MEMORY_SCOPE_AGENT);
        if ((old & 15u) == 15u){
            unsigned rold = __hip_atomic_fetch_add(bar + 32, 1u, __ATOMIC_RELAXED, __HIP_MEMORY_SCOPE_AGENT);
            if ((rold & 31u) == 31u){
                __hip_atomic_store(bar, n + 1u, __ATOMIC_RELEASE, __HIP_MEMORY_SCOPE_AGENT);
            }
        }
        int spins = 0;
        while (__hip_atomic_load(bar, __ATOMIC_RELAXED, __HIP_MEMORY_SCOPE_AGENT) < n + 1u){
            __builtin_amdgcn_s_sleep(4);
            if (++spins > 1024){
                (void)__hip_atomic_load(bar, __ATOMIC_ACQUIRE, __HIP_MEMORY_SCOPE_AGENT);
                spins = 0;
            }
        }
    }
    __syncthreads();
}

// stage A[16][96] f32 slice into LDS (coherent or plain source)
__device__ __forceinline__ void stageA(
    const float* Aptr, int ars, int aco, int k0, bool coh, float* Ash, int tid)
{
    #pragma unroll
    for (int rep = 0; rep < 3; rep++){
        int i2 = tid + rep*256;                  // 768 f2 chunks
        int r = i2 / 48, kk = (i2 % 48)*2;
        const float* src = Aptr + (size_t)r*ars + aco + k0 + kk;
        float2 v;
        if (coh) v = ld2a(src); else v = *(const float2*)src;
        Ash[r*96 + kk]     = v.x;
        Ash[r*96 + kk + 1] = v.y;
    }
    __syncthreads();
}

// f32-weight tile matmul: out[16][cbase..cbase+127] partial over k0..k0+95.
// thread: 1 row x 8 cols; 4-k-row bursts (8 dwordx4 loads in flight).
__device__ __forceinline__ void mm96f(
    const float* W, int N, float* outP, int cbase, int k0,
    const float* Ash, int tid)
{
    int cg = tid & 15, rg = tid >> 4;
    int col = cbase + cg*8;
    f32x4 accA = {0,0,0,0}, accB = {0,0,0,0};
    const float* Wc = W + (size_t)k0*N + col;
    const float* Arow = Ash + rg*96;
    for (int kb = 0; kb < 96; kb += 4){
        f32x4 w0a = *(const f32x4*)(Wc + (size_t)(kb+0)*N);
        f32x4 w0b = *(const f32x4*)(Wc + (size_t)(kb+0)*N + 4);
        f32x4 w1a = *(const f32x4*)(Wc + (size_t)(kb+1)*N);
        f32x4 w1b = *(const f32x4*)(Wc + (size_t)(kb+1)*N + 4);
        f32x4 w2a = *(const f32x4*)(Wc + (size_t)(kb+2)*N);
        f32x4 w2b = *(const f32x4*)(Wc + (size_t)(kb+2)*N + 4);
        f32x4 w3a = *(const f32x4*)(Wc + (size_t)(kb+3)*N);
        f32x4 w3b = *(const f32x4*)(Wc + (size_t)(kb+3)*N + 4);
        float a0 = Arow[kb], a1 = Arow[kb+1], a2 = Arow[kb+2], a3 = Arow[kb+3];
        accA += a0*w0a + a1*w1a + a2*w2a + a3*w3a;
        accB += a0*w0b + a1*w1b + a2*w2b + a3*w3b;
    }
    float* o = outP + (size_t)rg*N + col;
    st2a(o,   accA.x, accA.y); st2a(o+2, accA.z, accA.w);
    st2a(o+4, accB.x, accB.y); st2a(o+6, accB.z, accB.w);
}

__device__ __forceinline__ float bsum4(float v, float* red, int tid){
    #pragma unroll
    for (int off = 32; off; off >>= 1) v += __shfl_xor(v, off);
    __syncthreads();
    if ((tid & 63) == 0) red[tid >> 6] = v;
    __syncthreads();
    float s = red[0]+red[1]+red[2]+red[3];
    __syncthreads();
    return s;
}

__global__ __launch_bounds__(NTHR, 2) void coop_kernel(Params p)
{
    __shared__ float smem[6936];
    const int tid = threadIdx.x;
    const int bid = blockIdx.x;
    unsigned n = 0;

    {
        int gid = bid*NTHR + tid;
        if (gid < 24576) st2a(p.h + gid*2, 0.f, 0.f);   // h then c, contiguous
        if (gid < 2048)  p.out[(size_t)16*128*768 + gid] = p.mask_p[gid];
    }
    gsync(p.bar, bid, n); n++;

    for (int t = 0; t < 128; ++t){
        for (int d = 0; d < 2; ++d){
            const float* h_d = p.h + (size_t)d*12288;

            // ===== S1: h/cur weight matmuls =====
            // d=0: 30 tiles (6 Wr + 24 Whh) x 8kc = 240 blocks (Wp/Wih_cur precomputed)
            // d=1: 60 tiles (6 Wr + 6 Wp + 24 Whh + 24 Wih_cur) x 8kc = 480 blocks
            {
                int ntile = (d == 0) ? 30 : 60;
                if (bid < ntile*8){
                    int tile = bid >> 3, kc = bid & 7, k0 = kc*96;
                    if (d == 0){
                        stageA(h_d, 768, 0, k0, true, smem, tid);
                        if (tile < 6){
                            mm96f(p.Wr, 768, p.sP + (size_t)kc*12288, tile*128, k0, smem, tid);
                        } else {
                            mm96f(p.W_hh, 3072, p.whP + (size_t)kc*49152, (tile-6)*128, k0, smem, tid);
                        }
                    } else {
                        bool useCur = (tile >= 6 && tile < 12) || (tile >= 36);
                        stageA(useCur ? p.h : h_d, 768, 0, k0, true, smem, tid);
                        if (tile < 6){
                            mm96f(p.Wr + (size_t)589824, 768,
                                  p.sP + (size_t)kc*12288, tile*128, k0, smem, tid);
                        } else if (tile < 12){
                            mm96f(p.Wp + (size_t)589824, 768,
                                  p.sP + (size_t)(8+kc)*12288, (tile-6)*128, k0, smem, tid);
                        } else if (tile < 36){
                            mm96f(p.W_hh + (size_t)2359296, 3072,
                                  p.whP + (size_t)kc*49152, (tile-12)*128, k0, smem, tid);
                        } else {
                            mm96f(p.W_ih + (size_t)4718592, 3072,
                                  p.cwP + (size_t)kc*49152, (tile-36)*128, k0, smem, tid);
                        }
                    }
                }
            }
            gsync(p.bar, bid, n); n++;

            // ===== S2a: scores (256 blocks: 16 per batch, 8 scores each) =====
            if (bid < 256){
                int b = bid >> 4, sq0 = (bid & 15)*8;
                float* s_sh  = smem;
                float* wa_sh = smem + 768;
                if (tid < 192){
                    f32x4 acc = *(const f32x4*)(p.b_att + d*768 + tid*4);
                    if (d == 0){
                        f32x4 pv = *(const f32x4*)(p.pWp0 + ((size_t)b*128 + t)*768 + tid*4);
                        acc += pv;
                    }
                    int ncp = (d == 0) ? 8 : 16;
                    for (int cp = 0; cp < ncp; cp++){
                        const float* src = p.sP + (size_t)cp*12288 + b*768 + tid*4;
                        float2 u0 = ld2a(src);
                        float2 u1 = ld2a(src + 2);
                        acc.x += u0.x; acc.y += u0.y; acc.z += u1.x; acc.w += u1.y;
                    }
                    *(f32x4*)&s_sh[tid*4] = acc;
                } else {
                    int i0 = tid - 192;
                    for (int r = 0; r < 3; r++){
                        int i = i0 + r*64;
                        *(f32x4*)&wa_sh[i*4] = *(const f32x4*)(p.w_att + d*768 + i*4);
                    }
                }
                __syncthreads();
                int sq = sq0 + (tid >> 5), l = tid & 31;
                const float* qrow = p.qWq + ((size_t)(d*2048 + b*128 + sq))*768;
                float part = 0.f;
                #pragma unroll
                for (int i = 0; i < 6; i++){
                    int a = i*128 + l*4;
                    f32x4 q  = *(const f32x4*)(qrow + a);
                    f32x4 s4 = *(const f32x4*)(s_sh + a);
                    f32x4 w4 = *(const f32x4*)(wa_sh + a);
                    part += ftanh(q.x + s4.x)*w4.x + ftanh(q.y + s4.y)*w4.y
                          + ftanh(q.z + s4.z)*w4.z + ftanh(q.w + s4.w)*w4.w;
                }
                #pragma unroll
                for (int off = 16; off; off >>= 1) part += __shfl_xor(part, off, 32);
                if (l == 0){
                    float e = (p.mask_q[b*128 + sq] > 0.f) ? __expf(part) : 0.f;
                    st1a(p.escore + b*128 + sq, e);
                }
            }
            gsync(p.bar, bid, n); n++;

            // ===== S2b: weighted (64 blocks) + wh/cw partial-reduce (96 blocks) =====
            if (bid < 64){
                int b = bid >> 2, cg = bid & 3;
                float* e_sh = smem;    // 129
                if (tid < 128) e_sh[tid] = ld1a(p.escore + b*128 + tid);
                __syncthreads();
                if (tid < 64){
                    float v = e_sh[tid] + e_sh[tid + 64];
                    #pragma unroll
                    for (int off = 32; off; off >>= 1) v += __shfl_xor(v, off);
                    if (tid == 0) e_sh[128] = 1.0f / v;
                }
                __syncthreads();
                float inv = e_sh[128];
                if (tid < 192){
                    int cc = cg*192 + tid;
                    const float* ip = p.iqT + ((size_t)b*768 + cc)*128;
                    float acc = 0.f;
                    #pragma unroll 8
                    for (int j = 0; j < 32; j++){
                        f32x4 q  = *(const f32x4*)(ip + j*4);
                        f32x4 e4 = *(const f32x4*)&e_sh[j*4];
                        acc += dot4(q, e4);
                    }
                    st1a(p.wghtd + b*768 + cc, acc*inv);
                }
            } else if (bid < 160){
                int gid = (bid - 64)*NTHR + tid;   // < 24576
                int which = gid / 12288;
                int i4 = gid % 12288;
                if (which == 0 || d == 1){         // cw reduce only needed for d=1
                    const float* src = which ? p.cwP : p.whP;
                    float* dst = which ? p.cwR : p.whR;
                    float2 a0 = {0.f,0.f}, a1 = {0.f,0.f};
                    #pragma unroll
                    for (int cp = 0; cp < 8; cp++){
                        const float* s0 = src + (size_t)cp*49152 + i4*4;
                        float2 u0 = ld2a(s0);
                        float2 u1 = ld2a(s0 + 2);
                        a0.x += u0.x; a0.y += u0.y; a1.x += u1.x; a1.y += u1.y;
                    }
                    st2a(dst + i4*4,     a0.x, a0.y);
                    st2a(dst + i4*4 + 2, a1.x, a1.y);
                }
            }
            gsync(p.bar, bid, n); n++;

            // ===== S3: wi matmul (192 blocks: 24 tiles x 8kc) =====
            if (bid < 192){
                int tile = bid >> 3, kc = bid & 7, k0 = kc*96;
                stageA(p.wghtd, 768, 0, k0, true, smem, tid);
                mm96f(p.W_ih + (size_t)d*4718592 + (size_t)768*3072, 3072,
                      p.wiP + (size_t)kc*49152, tile*128, k0, smem, tid);
            }
            gsync(p.bar, bid, n); n++;

            // ===== S4: LN + gates (16 blocks) =====
            if (bid < 16){
                const int b = bid;
                float* wi_sh = smem;           // 3072
                float* wh_sh = smem + 3072;    // 3072
                float* c_sh  = smem + 6144;    // 768
                float* red   = smem + 6928;    // 4
                const float mm = p.mask_p[b*128 + t];
                const float* gi = p.ln_i_g + d*3072; const float* bi = p.ln_i_b + d*3072;
                const float* gh = p.ln_h_g + d*3072; const float* bh = p.ln_h_b + d*3072;
                const float* gc = p.ln_c_g + d*768;  const float* bc = p.ln_c_b + d*768;
                const float* bias_d = p.bias + d*3072;

                float swi=0,qwi=0,swh=0,qwh=0;
                #pragma unroll
                for (int rep = 0; rep < 3; rep++){
                    int j4 = tid + rep*256;
                    int base = b*3072 + j4*4;
                    f32x4 a = {0,0,0,0};
                    #pragma unroll
                    for (int cp = 0; cp < 8; cp++){
                        const float* s0 = p.wiP + (size_t)cp*49152 + base;
                        float2 u0 = ld2a(s0);
                        float2 u1 = ld2a(s0 + 2);
                        a.x += u0.x; a.y += u0.y; a.z += u1.x; a.w += u1.y;
                    }
                    if (d == 0){
                        f32x4 pv = *(const f32x4*)(p.pWih0 + ((size_t)b*128 + t)*3072 + j4*4);
                        a += pv;
                    } else {
                        float2 cw0 = ld2a(p.cwR + base), cw1 = ld2a(p.cwR + base + 2);
                        a.x += cw0.x; a.y += cw0.y; a.z += cw1.x; a.w += cw1.y;
                    }
                    float2 wh0 = ld2a(p.whR + base), wh1 = ld2a(p.whR + base + 2);
                    f32x4 hvec = { wh0.x, wh0.y, wh1.x, wh1.y };
                    *(f32x4*)&wi_sh[j4*4] = a;
                    *(f32x4*)&wh_sh[j4*4] = hvec;
                    swi += a.x+a.y+a.z+a.w;
                    qwi += dot4(a,a);
                    swh += hvec.x+hvec.y+hvec.z+hvec.w;
                    qwh += dot4(hvec,hvec);
                }
                swi = bsum4(swi, red, tid);
                qwi = bsum4(qwi, red, tid);
                swh = bsum4(swh, red, tid);
                qwh = bsum4(qwh, red, tid);
                float mi = swi/3072.f, vi = fmaxf((qwi - 3072.f*mi*mi)/3071.f, 0.f);
                float mh = swh/3072.f, vh = fmaxf((qwh - 3072.f*mh*mh)/3071.f, 0.f);
                float ivi = 1.f/(sqrtf(vi + 1e-6f) + 1e-6f);
                float ivh = 1.f/(sqrtf(vh + 1e-6f) + 1e-6f);

                for (int j = tid; j < 3072; j += NTHR){
                    float pre = mm*(gi[j]*(wi_sh[j]-mi)*ivi + bi[j])
                              + mm*(gh[j]*(wh_sh[j]-mh)*ivh + bh[j])
                              + bias_d[j];
                    wi_sh[j] = pre;
                }
                __syncthreads();

                float sc=0,qc=0;
                for (int idx = tid; idx < 384; idx += NTHR){
                    int u = idx*2;
                    float2 c_old = ld2a(p.c + (size_t)d*12288 + b*768 + u);
                    float f0  = wi_sh[u],        f1  = wi_sh[u+1];
                    float i0  = wi_sh[768+u],    i1  = wi_sh[768+u+1];
                    float g0  = wi_sh[2304+u],   g1  = wi_sh[2304+u+1];
                    float c10 = fsigmoid(f0)*c_old.x + fsigmoid(i0)*ftanh(g0);
                    float c11 = fsigmoid(f1)*c_old.y + fsigmoid(i1)*ftanh(g1);
                    c10 = c10*mm + c_old.x*(1.f - mm);
                    c11 = c11*mm + c_old.y*(1.f - mm);
                    st2a(p.c + (size_t)d*12288 + b*768 + u, c10, c11);
                    c_sh[u] = c10; c_sh[u+1] = c11;
                    sc += c10 + c11; qc += c10*c10 + c11*c11;
                }
                sc = bsum4(sc, red, tid);
                qc = bsum4(qc, red, tid);
                float mc = sc/768.f, vc = fmaxf((qc - 768.f*mc*mc)/767.f, 0.f);
                float ivc = 1.f/(sqrtf(vc + 1e-6f) + 1e-6f);

                for (int idx = tid; idx < 384; idx += NTHR){
                    int u = idx*2;
                    float2 h_old = ld2a(p.h + (size_t)d*12288 + b*768 + u);
                    float o0 = wi_sh[1536+u], o1 = wi_sh[1536+u+1];
                    float l0 = (gc[u]*(c_sh[u]-mc)*ivc + bc[u])*mm;
                    float l1 = (gc[u+1]*(c_sh[u+1]-mc)*ivc + bc[u+1])*mm;
                    float h10 = fsigmoid(o0)*ftanh(l0);
                    float h11 = fsigmoid(o1)*ftanh(l1);
                    h10 = h10*mm + h_old.x*(1.f - mm);
                    h11 = h11*mm + h_old.y*(1.f - mm);
                    st2a(p.h + (size_t)d*12288 + b*768 + u, h10, h11);
                    if (d == 1){
                        float2 ov = { h10, h11 };
                        *(float2*)(p.out + ((size_t)b*128 + t)*768 + u) = ov;
                    }
                }
            }
            gsync(p.bar, bid, n); n++;
        }
    }
}

// ---------- precompute GEMM (f32 out; validated R0/R1/R5 kernel) ----------
__global__ __launch_bounds__(256) void k_mm_pre(
    const float* __restrict__ Ain, const float* __restrict__ W,
    float* __restrict__ C, int ldw, int ncols)
{
    __shared__ float Ash[16][772];
    int rowbase = blockIdx.y*16;
    for (int r = 0; r < 16; r++)
        for (int i = threadIdx.x; i < 768; i += 256)
            Ash[r][i] = Ain[(size_t)(rowbase + r)*768 + i];
    __syncthreads();
    int lane = threadIdx.x & 63;
    int colq = lane & 15, rsub = lane >> 4, wq = threadIdx.x >> 6;
    int r = wq*4 + rsub;
    int col = blockIdx.x*64 + colq*4;
    float4 acc = {0.f,0.f,0.f,0.f};
    const float* Wc = W + col;
    for (int k = 0; k < 768; k += 4){
        float4 a4 = *(const float4*)&Ash[r][k];
        float4 w0 = *(const float4*)(Wc + (size_t)(k+0)*ldw);
        float4 w1 = *(const float4*)(Wc + (size_t)(k+1)*ldw);
        float4 w2 = *(const float4*)(Wc + (size_t)(k+2)*ldw);
        float4 w3 = *(const float4*)(Wc + (size_t)(k+3)*ldw);
        acc.x += a4.x*w0.x + a4.y*w1.x + a4.z*w2.x + a4.w*w3.x;
        acc.y += a4.x*w0.y + a4.y*w1.y + a4.z*w2.y + a4.w*w3.y;
        acc.z += a4.x*w0.z + a4.y*w1.z + a4.z*w2.z + a4.w*w3.z;
        acc.w += a4.x*w0.w + a4.y*w1.w + a4.z*w2.w + a4.w*w3.w;
    }
    *(float4*)(C + (size_t)(rowbase + r)*ncols + col) = acc;
}

// ---------- transpose input_q -> iqT[b][c][sq] f32 ----------
__global__ __launch_bounds__(256) void k_transq(
    const float* __restrict__ iq, float* __restrict__ iqT)
{
    __shared__ float Tsh[32][136];
    int c0 = blockIdx.x*32, b = blockIdx.y;
    for (int rep = 0; rep < 4; rep++){
        int idx = threadIdx.x + rep*256;
        int sq = idx >> 3, cq = idx & 7;
        float4 v = *(const float4*)(iq + ((size_t)b*128 + sq)*768 + c0 + cq*4);
        Tsh[cq*4+0][sq] = v.x;
        Tsh[cq*4+1][sq] = v.y;
        Tsh[cq*4+2][sq] = v.z;
        Tsh[cq*4+3][sq] = v.w;
    }
    __syncthreads();
    for (int rep = 0; rep < 4; rep++){
        int idx = threadIdx.x + rep*256;
        int cl = idx >> 5, sq4 = (idx & 31)*4;
        float4 v = *(const float4*)&Tsh[cl][sq4];
        *(float4*)(iqT + ((size_t)b*768 + c0 + cl)*128 + sq4) = v;
    }
}

extern "C" void kernel_launch(void* const* d_in, const int* in_sizes, int n_in,
                              void* d_out, int out_size, void* d_ws, size_t ws_size,
                              hipStream_t stream)
{
    (void)in_sizes; (void)n_in; (void)out_size; (void)ws_size;
    Params P;
    P.input_p = (const float*)d_in[0];
    P.mask_p  = (const float*)d_in[1];
    P.input_q = (const float*)d_in[2];
    P.mask_q  = (const float*)d_in[3];
    P.W_ih    = (const float*)d_in[4];
    P.W_hh    = (const float*)d_in[5];
    P.bias    = (const float*)d_in[6];
    P.ln_i_g  = (const float*)d_in[7];
    P.ln_i_b  = (const float*)d_in[8];
    P.ln_h_g  = (const float*)d_in[9];
    P.ln_h_b  = (const float*)d_in[10];
    P.ln_c_g  = (const float*)d_in[11];
    P.ln_c_b  = (const float*)d_in[12];
    P.Wq      = (const float*)d_in[13];
    P.Wp      = (const float*)d_in[14];
    P.Wr      = (const float*)d_in[15];
    P.w_att   = (const float*)d_in[16];
    P.b_att   = (const float*)d_in[17];
    P.out     = (float*)d_out;

    float* ws = (float*)d_ws;
    size_t off = 0;
    auto alloc = [&](size_t nfloat)->float*{
        float* r = ws + off;
        off += (nfloat + 63) & ~(size_t)63;
        return r;
    };
    P.qWq    = alloc((size_t)2*2048*768);
    P.iqT    = alloc((size_t)16*768*128);
    P.pWp0   = alloc((size_t)2048*768);
    P.pWih0  = alloc((size_t)2048*3072);
    P.h      = alloc(24576);
    P.c      = alloc(24576);          // contiguous after h
    P.sP     = alloc((size_t)16*16*768);
    P.whP    = alloc((size_t)8*16*3072);
    P.cwP    = alloc((size_t)8*16*3072);
    P.wiP    = alloc((size_t)8*16*3072);
    P.whR    = alloc(49152);
    P.cwR    = alloc(49152);
    P.wghtd  = alloc(12288);
    P.escore = alloc(2048);
    P.bar    = (unsigned*)alloc(2048);

    hipMemsetAsync((void*)P.bar, 0, 2048*sizeof(unsigned), stream);
    k_mm_pre<<<dim3(12,128), 256, 0, stream>>>(P.input_q, P.Wq, P.qWq, 768, 768);
    k_mm_pre<<<dim3(12,128), 256, 0, stream>>>(P.input_q, P.Wq + (size_t)589824,
                                               P.qWq + (size_t)2048*768, 768, 768);
    k_mm_pre<<<dim3(12,128), 256, 0, stream>>>(P.input_p, P.Wp, P.pWp0, 768, 768);
    k_mm_pre<<<dim3(48,128), 256, 0, stream>>>(P.input_p, P.W_ih, P.pWih0, 3072, 3072);
    k_transq<<<dim3(24,16), 256, 0, stream>>>(P.input_q, P.iqT);
    coop_kernel<<<dim3(NBLK), dim3(NTHR), 0, stream>>>(P);
}